// Round 1
// baseline (1197.007 us; speedup 1.0000x reference)
//
#include <hip/hip_runtime.h>
#include <math.h>

#define NB 16
#define NC 21
#define NANCH 65536
#define NM 20

#define POS_THR 0.5f
#define NEG_THR 0.4f
#define F_ALPHA 0.25f
#define MIN_POS_TOPK 10
#define NEG_POS_RATIO 3

// ---------- helpers ----------
__device__ __forceinline__ void decode_box(const float* __restrict__ anchors,
                                           const float* __restrict__ reg,
                                           int b, int n, float out[4]) {
  const float* ap = anchors + (size_t)n * 4;
  float ax1 = ap[0], ay1 = ap[1], ax2 = ap[2], ay2 = ap[3];
  float aw = ax2 - ax1, ah = ay2 - ay1;
  float acx = ax1 + 0.5f * aw, acy = ay1 + 0.5f * ah;
  size_t base = ((size_t)b * 4) * NANCH + n;
  float dx = reg[base];
  float dy = reg[base + (size_t)NANCH];
  float dw = reg[base + 2 * (size_t)NANCH];
  float dh = reg[base + 3 * (size_t)NANCH];
  float cx = acx + dx * aw, cy = acy + dy * ah;
  float w = aw * expf(dw), h = ah * expf(dh);
  out[0] = cx - 0.5f * w;
  out[1] = cy - 0.5f * h;
  out[2] = cx + 0.5f * w;
  out[3] = cy + 0.5f * h;
}

// ---------- K0: zero the accumulators ----------
__global__ void k_init(int* pos_cnt, int* neg_cnt, float* sums) {
  int t = threadIdx.x;
  if (t < NB) { pos_cnt[t] = 0; neg_cnt[t] = 0; }
  if (t < 3 * NB) sums[t] = 0.0f;
}

// ---------- K1: decode + pairwise IoU max/argmax + pos/neg counts ----------
__global__ __launch_bounds__(256)
void k_iou(const float* __restrict__ reg, const float* __restrict__ anchors,
           const float* __restrict__ tb,
           float* __restrict__ miou, int* __restrict__ midx,
           int* __restrict__ pos_cnt, int* __restrict__ neg_cnt) {
  __shared__ float tbs[NM * 4];
  __shared__ int s_pos, s_neg;
  int b = blockIdx.x >> 8;                       // 256 blocks per image
  int n = ((blockIdx.x & 255) << 8) | threadIdx.x;
  if (threadIdx.x < NM * 4) tbs[threadIdx.x] = tb[(size_t)b * NM * 4 + threadIdx.x];
  if (threadIdx.x == 0) { s_pos = 0; s_neg = 0; }
  __syncthreads();

  float d[4];
  decode_box(anchors, reg, b, n, d);
  float area_a = (d[2] - d[0]) * (d[3] - d[1]);

  float best = -1.0f;
  int bidx = 0;
  for (int m = 0; m < NM; ++m) {
    float bx1 = tbs[m * 4 + 0], by1 = tbs[m * 4 + 1];
    float bx2 = tbs[m * 4 + 2], by2 = tbs[m * 4 + 3];
    float area_b = (bx2 - bx1) * (by2 - by1);
    float lx = fmaxf(d[0], bx1), ly = fmaxf(d[1], by1);
    float rx = fminf(d[2], bx2), ry = fminf(d[3], by2);
    float iw = fmaxf(rx - lx, 0.0f), ih = fmaxf(ry - ly, 0.0f);
    float inter = iw * ih;
    float uni = area_a + area_b - inter;
    float iou = inter / fmaxf(uni, 1e-7f);
    if (iou > best) { best = iou; bidx = m; }   // first-max wins (jnp.argmax)
  }
  size_t idx = (size_t)b * NANCH + n;
  miou[idx] = best;
  midx[idx] = bidx;

  if (best >= POS_THR) atomicAdd(&s_pos, 1);
  if (best < NEG_THR)  atomicAdd(&s_neg, 1);
  __syncthreads();
  if (threadIdx.x == 0) {
    if (s_pos) atomicAdd(&pos_cnt[b], s_pos);
    if (s_neg) atomicAdd(&neg_cnt[b], s_neg);
  }
}

// ---------- K2: exact top-10 (value desc, index asc tie-break) ----------
__global__ __launch_bounds__(256)
void k_top10(const float* __restrict__ miou, const int* __restrict__ pos_cnt,
             int* __restrict__ num_pos, int* __restrict__ use_fb,
             int* __restrict__ top10) {
  int b = blockIdx.x;
  const float* mi = miou + (size_t)b * NANCH;
  __shared__ float sv[256];
  __shared__ int   si[256];
  __shared__ int   sel[MIN_POS_TOPK];

  for (int it = 0; it < MIN_POS_TOPK; ++it) {
    float bv = -1.0f;
    int bi = NANCH;
    for (int n = threadIdx.x; n < NANCH; n += 256) {
      bool skip = false;
      for (int s = 0; s < it; ++s) if (sel[s] == n) skip = true;
      if (skip) continue;
      float v = mi[n];
      if (v > bv || (v == bv && n < bi)) { bv = v; bi = n; }
    }
    sv[threadIdx.x] = bv;
    si[threadIdx.x] = bi;
    __syncthreads();
    if (threadIdx.x == 0) {
      float bestv = -1.0f; int besti = NANCH;
      for (int t = 0; t < 256; ++t) {
        if (sv[t] > bestv || (sv[t] == bestv && si[t] < besti)) { bestv = sv[t]; besti = si[t]; }
      }
      sel[it] = besti;
    }
    __syncthreads();
  }
  if (threadIdx.x < MIN_POS_TOPK) top10[b * MIN_POS_TOPK + threadIdx.x] = sel[threadIdx.x];
  if (threadIdx.x == 0) {
    int pc = pos_cnt[b];
    int fb = (pc < MIN_POS_TOPK) ? 1 : 0;
    use_fb[b] = fb;
    num_pos[b] = fb ? MIN_POS_TOPK : pc;
  }
}

// ---------- K3: negative subsampling threshold (exact k-th smallest with ties) ----------
#define EQCAP 1024
__global__ __launch_bounds__(256)
void k_negsel(const float* __restrict__ miou, const float* __restrict__ scores,
              const int* __restrict__ neg_cnt, const int* __restrict__ num_pos,
              int* __restrict__ subsample, unsigned* __restrict__ vbits_out,
              int* __restrict__ idx_cut, int* __restrict__ total_samples) {
  int b = blockIdx.x;
  const float* mi = miou + (size_t)b * NANCH;
  const float* sc = scores + (size_t)b * NANCH;
  int np = num_pos[b];
  int nc = neg_cnt[b];
  int k = NEG_POS_RATIO * np;

  if (nc <= k) {
    if (threadIdx.x == 0) {
      subsample[b] = 0;
      vbits_out[b] = 0u;
      idx_cut[b] = -1;
      total_samples[b] = np + nc;
    }
    return;
  }

  __shared__ unsigned hist[256];
  __shared__ unsigned s_prefix;
  __shared__ int s_kr;
  if (threadIdx.x == 0) { s_prefix = 0u; s_kr = k; }
  __syncthreads();

  for (int p = 0; p < 4; ++p) {
    int shift = 24 - 8 * p;
    if (threadIdx.x < 256) hist[threadIdx.x] = 0u;
    __syncthreads();
    unsigned prefix = s_prefix;
    for (int n = threadIdx.x; n < NANCH; n += 256) {
      if (mi[n] < NEG_THR) {
        unsigned bits = __float_as_uint(sc[n]);
        bool hi_match = (p == 0) || ((bits >> (shift + 8)) == (prefix >> (shift + 8)));
        if (hi_match) atomicAdd(&hist[(bits >> shift) & 0xFFu], 1u);
      }
    }
    __syncthreads();
    if (threadIdx.x == 0) {
      unsigned cum = 0;
      int chosen = 255;
      for (int bkt = 0; bkt < 256; ++bkt) {
        if (cum + hist[bkt] >= (unsigned)s_kr) { chosen = bkt; break; }
        cum += hist[bkt];
      }
      s_prefix |= ((unsigned)chosen) << shift;
      s_kr -= (int)cum;
    }
    __syncthreads();
  }

  // gather indices with score bits == k-th value, pick the s_kr smallest indices
  __shared__ int eq_list[EQCAP];
  __shared__ int eq_cnt;
  if (threadIdx.x == 0) eq_cnt = 0;
  __syncthreads();
  unsigned vb = s_prefix;
  for (int n = threadIdx.x; n < NANCH; n += 256) {
    if (mi[n] < NEG_THR && __float_as_uint(sc[n]) == vb) {
      int slot = atomicAdd(&eq_cnt, 1);
      if (slot < EQCAP) eq_list[slot] = n;
    }
  }
  __syncthreads();
  if (threadIdx.x == 0) {
    int E = eq_cnt < EQCAP ? eq_cnt : EQCAP;
    int ne = s_kr;
    if (ne > E) ne = E;
    if (ne < 1) ne = 1;
    // partial selection sort: find ne smallest indices
    for (int i = 0; i < ne; ++i) {
      int mn = i;
      for (int j = i + 1; j < E; ++j) if (eq_list[j] < eq_list[mn]) mn = j;
      int t = eq_list[i]; eq_list[i] = eq_list[mn]; eq_list[mn] = t;
    }
    subsample[b] = 1;
    vbits_out[b] = vb;
    idx_cut[b] = eq_list[ne - 1];
    total_samples[b] = np + k;
  }
}

// ---------- K4: per-anchor loss accumulation ----------
__global__ __launch_bounds__(256)
void k_loss(const float* __restrict__ cls, const float* __restrict__ reg,
            const float* __restrict__ anchors, const float* __restrict__ tb,
            const int* __restrict__ tl, const float* __restrict__ scores,
            const float* __restrict__ miou, const int* __restrict__ midx,
            const int* __restrict__ use_fb, const int* __restrict__ top10,
            const int* __restrict__ subsample, const unsigned* __restrict__ vbits,
            const int* __restrict__ idx_cut,
            float* __restrict__ sums /* [NB][3] : pos, neg, reg */) {
  int b = blockIdx.x >> 8;
  int n = ((blockIdx.x & 255) << 8) | threadIdx.x;
  __shared__ int s_top10[MIN_POS_TOPK];
  __shared__ int s_usefb, s_sub, s_cut;
  __shared__ unsigned s_vb;
  __shared__ float accp, accn, accr;
  if (threadIdx.x < MIN_POS_TOPK) s_top10[threadIdx.x] = top10[b * MIN_POS_TOPK + threadIdx.x];
  if (threadIdx.x == 0) {
    s_usefb = use_fb[b]; s_sub = subsample[b]; s_cut = idx_cut[b]; s_vb = vbits[b];
    accp = 0.0f; accn = 0.0f; accr = 0.0f;
  }
  __syncthreads();

  size_t idx = (size_t)b * NANCH + n;
  float mi = miou[idx];
  int mx = midx[idx];

  bool pos;
  if (s_usefb) {
    pos = false;
    #pragma unroll
    for (int i = 0; i < MIN_POS_TOPK; ++i) pos |= (s_top10[i] == n);
  } else {
    pos = (mi >= POS_THR);
  }
  bool neg = (mi < NEG_THR);
  bool nsel = false;
  if (neg) {
    if (!s_sub) nsel = true;
    else {
      unsigned sb = __float_as_uint(scores[idx]);
      nsel = (sb < s_vb) || (sb == s_vb && n <= s_cut);
    }
  }

  float cp = 0.0f, cn = 0.0f, rg = 0.0f;
  if (pos || nsel) {
    int t = 0;
    if (pos) t = tl[b * NM + mx];
    size_t cb = ((size_t)b * NC) * NANCH + n;
    float mxl = -3.0e38f, l0 = 0.0f, lt = 0.0f;
    for (int c = 0; c < NC; ++c) {
      float l = cls[cb + (size_t)c * NANCH];
      if (c == 0) l0 = l;
      if (c == t) lt = l;
      mxl = fmaxf(mxl, l);
    }
    float se = 0.0f;
    for (int c = 0; c < NC; ++c) {
      float l = cls[cb + (size_t)c * NANCH];
      se += expf(l - mxl);
    }
    float lse = mxl + logf(se);
    if (nsel) {
      float ce = lse - l0;
      float pt = expf(-ce);
      float om = 1.0f - pt;
      cn = F_ALPHA * om * om * ce;
    }
    if (pos) {
      float ce = lse - lt;
      float pt = expf(-ce);
      float om = 1.0f - pt;
      cp = F_ALPHA * om * om * ce;
      // GIoU vs matched GT
      float d[4];
      decode_box(anchors, reg, b, n, d);
      const float* g = tb + ((size_t)b * NM + mx) * 4;
      float gx1 = g[0], gy1 = g[1], gx2 = g[2], gy2 = g[3];
      float area_a = (d[2] - d[0]) * (d[3] - d[1]);
      float area_b = (gx2 - gx1) * (gy2 - gy1);
      float lx = fmaxf(d[0], gx1), ly = fmaxf(d[1], gy1);
      float rx = fminf(d[2], gx2), ry = fminf(d[3], gy2);
      float iw = fmaxf(rx - lx, 0.0f), ih = fmaxf(ry - ly, 0.0f);
      float inter = iw * ih;
      float uni = area_a + area_b - inter;
      float iou = inter / fmaxf(uni, 1e-7f);
      float ex1 = fminf(d[0], gx1), ey1 = fminf(d[1], gy1);
      float ex2 = fmaxf(d[2], gx2), ey2 = fmaxf(d[3], gy2);
      float ew = fmaxf(ex2 - ex1, 0.0f), eh = fmaxf(ey2 - ey1, 0.0f);
      float enc = ew * eh;
      float giou = iou - (enc - uni) / fmaxf(enc, 1e-7f);
      rg = 1.0f - giou;
    }
  }

  if (cp != 0.0f) atomicAdd(&accp, cp);
  if (cn != 0.0f) atomicAdd(&accn, cn);
  if (rg != 0.0f) atomicAdd(&accr, rg);
  __syncthreads();
  if (threadIdx.x == 0) {
    if (accp != 0.0f) atomicAdd(&sums[b * 3 + 0], accp);
    if (accn != 0.0f) atomicAdd(&sums[b * 3 + 1], accn);
    if (accr != 0.0f) atomicAdd(&sums[b * 3 + 2], accr);
  }
}

// ---------- K5: finalize ----------
__global__ void k_final(const float* __restrict__ sums,
                        const int* __restrict__ total_samples,
                        const int* __restrict__ num_pos,
                        float* __restrict__ out) {
  if (threadIdx.x == 0 && blockIdx.x == 0) {
    float cm = 0.0f, rm = 0.0f;
    for (int b = 0; b < NB; ++b) {
      int ts = total_samples[b]; if (ts < 1) ts = 1;
      int np = num_pos[b]; if (np < 1) np = 1;
      cm += (sums[b * 3 + 0] + sums[b * 3 + 1]) / (float)ts;
      rm += sums[b * 3 + 2] / (float)np;
    }
    out[0] = cm / (float)NB + rm / (float)NB;
  }
}

extern "C" void kernel_launch(void* const* d_in, const int* in_sizes, int n_in,
                              void* d_out, int out_size, void* d_ws, size_t ws_size,
                              hipStream_t stream) {
  const float* cls     = (const float*)d_in[0];
  const float* reg     = (const float*)d_in[1];
  const float* anchors = (const float*)d_in[2];
  const float* tb      = (const float*)d_in[3];
  const int*   tl      = (const int*)d_in[4];
  const float* scores  = (const float*)d_in[5];
  float* out = (float*)d_out;

  char* ws = (char*)d_ws;
  float* miou = (float*)ws;                                   // NB*NANCH floats
  int*   midx = (int*)(ws + (size_t)4 * NB * NANCH);          // NB*NANCH ints
  int*   scal = (int*)(ws + (size_t)8 * NB * NANCH);
  int* pos_cnt       = scal;
  int* neg_cnt       = scal + NB;
  int* num_pos       = scal + 2 * NB;
  int* use_fb        = scal + 3 * NB;
  int* subsample     = scal + 4 * NB;
  int* idx_cut       = scal + 5 * NB;
  unsigned* vbits    = (unsigned*)(scal + 6 * NB);
  int* total_samples = scal + 7 * NB;
  int* top10         = scal + 8 * NB;                         // NB*10
  float* sums        = (float*)(scal + 8 * NB + MIN_POS_TOPK * NB); // NB*3

  k_init<<<1, 256, 0, stream>>>(pos_cnt, neg_cnt, sums);
  k_iou<<<NB * 256, 256, 0, stream>>>(reg, anchors, tb, miou, midx, pos_cnt, neg_cnt);
  k_top10<<<NB, 256, 0, stream>>>(miou, pos_cnt, num_pos, use_fb, top10);
  k_negsel<<<NB, 256, 0, stream>>>(miou, scores, neg_cnt, num_pos,
                                   subsample, vbits, idx_cut, total_samples);
  k_loss<<<NB * 256, 256, 0, stream>>>(cls, reg, anchors, tb, tl, scores,
                                       miou, midx, use_fb, top10, subsample,
                                       vbits, idx_cut, sums);
  k_final<<<1, 1, 0, stream>>>(sums, total_samples, num_pos, out);
}

// Round 2
// 178.051 us; speedup vs baseline: 6.7228x; 6.7228x over previous
//
#include <hip/hip_runtime.h>
#include <math.h>
#include <limits.h>

#define NB 16
#define NC 21
#define NANCH 65536
#define NM 20

#define POS_THR 0.5f
#define NEG_THR 0.4f
#define F_ALPHA 0.25f
#define MIN_POS_TOPK 10
#define NEG_POS_RATIO 3

#define NBINS 65536
#define EQCAP 2048

// ---------- helpers ----------
__device__ __forceinline__ void decode_box(const float* __restrict__ anchors,
                                           const float* __restrict__ reg,
                                           int b, int n, float out[4]) {
  const float* ap = anchors + (size_t)n * 4;
  float ax1 = ap[0], ay1 = ap[1], ax2 = ap[2], ay2 = ap[3];
  float aw = ax2 - ax1, ah = ay2 - ay1;
  float acx = ax1 + 0.5f * aw, acy = ay1 + 0.5f * ah;
  size_t base = ((size_t)b * 4) * NANCH + n;
  float dx = reg[base];
  float dy = reg[base + (size_t)NANCH];
  float dw = reg[base + 2 * (size_t)NANCH];
  float dh = reg[base + 3 * (size_t)NANCH];
  float cx = acx + dx * aw, cy = acy + dy * ah;
  float w = aw * expf(dw), h = ah * expf(dh);
  out[0] = cx - 0.5f * w;
  out[1] = cy - 0.5f * h;
  out[2] = cx + 0.5f * w;
  out[3] = cy + 0.5f * h;
}

// wave(64)-wide argmax of (v desc, i asc)
__device__ __forceinline__ void argmax64(float& v, int& i) {
  #pragma unroll
  for (int m = 32; m >= 1; m >>= 1) {
    float ov = __shfl_xor(v, m, 64);
    int   oi = __shfl_xor(i, m, 64);
    if (ov > v || (ov == v && oi < i)) { v = ov; i = oi; }
  }
}

// ---------- K0: zero hist + scalar accumulators ----------
__global__ void k_init(unsigned* hist, int* pos_cnt, int* neg_cnt,
                       int* eqcnt, float* sums) {
  size_t tid = (size_t)blockIdx.x * blockDim.x + threadIdx.x;
  size_t tot = (size_t)NB * NBINS;
  for (size_t j = tid; j < tot; j += (size_t)gridDim.x * blockDim.x) hist[j] = 0u;
  if (blockIdx.x == 0) {
    int t = threadIdx.x;
    if (t < NB) { pos_cnt[t] = 0; neg_cnt[t] = 0; eqcnt[t] = 0; }
    if (t < 3 * NB) sums[t] = 0.0f;
  }
}

// ---------- K1: decode + IoU max/argmax + counts + score hist + block top-10 ----------
__global__ __launch_bounds__(256)
void k_iou(const float* __restrict__ reg, const float* __restrict__ anchors,
           const float* __restrict__ tb, const float* __restrict__ scores,
           float* __restrict__ miou, int* __restrict__ midx,
           int* __restrict__ pos_cnt, int* __restrict__ neg_cnt,
           unsigned* __restrict__ hist,
           float* __restrict__ cand_val, int* __restrict__ cand_idx) {
  __shared__ float tbs[NM * 4];
  __shared__ int s_pos, s_neg;
  __shared__ float swv[4];
  __shared__ int   swi[4];
  __shared__ float selv[MIN_POS_TOPK];
  __shared__ int   seli[MIN_POS_TOPK];
  int b   = blockIdx.x >> 8;
  int blk = blockIdx.x & 255;
  int n = (blk << 8) | threadIdx.x;
  if (threadIdx.x < NM * 4) tbs[threadIdx.x] = tb[(size_t)b * NM * 4 + threadIdx.x];
  if (threadIdx.x == 0) { s_pos = 0; s_neg = 0; }
  __syncthreads();

  float d[4];
  decode_box(anchors, reg, b, n, d);
  float area_a = (d[2] - d[0]) * (d[3] - d[1]);

  float best = -1.0f;
  int bidx = 0;
  #pragma unroll
  for (int m = 0; m < NM; ++m) {
    float bx1 = tbs[m * 4 + 0], by1 = tbs[m * 4 + 1];
    float bx2 = tbs[m * 4 + 2], by2 = tbs[m * 4 + 3];
    float area_b = (bx2 - bx1) * (by2 - by1);
    float lx = fmaxf(d[0], bx1), ly = fmaxf(d[1], by1);
    float rx = fminf(d[2], bx2), ry = fminf(d[3], by2);
    float iw = fmaxf(rx - lx, 0.0f), ih = fmaxf(ry - ly, 0.0f);
    float inter = iw * ih;
    float uni = area_a + area_b - inter;
    float iou = inter / fmaxf(uni, 1e-7f);
    if (iou > best) { best = iou; bidx = m; }   // first-max wins (jnp.argmax)
  }
  size_t idx = (size_t)b * NANCH + n;
  miou[idx] = best;
  midx[idx] = bidx;

  if (best >= POS_THR) atomicAdd(&s_pos, 1);
  if (best < NEG_THR) {
    atomicAdd(&s_neg, 1);
    unsigned bits = __float_as_uint(scores[idx]);
    atomicAdd(&hist[(size_t)b * NBINS + (bits >> 16)], 1u);
  }

  // ---- block-local top-10 of miou (value desc, index asc) ----
  float val = best;
  int wid = threadIdx.x >> 6;
  for (int it = 0; it < MIN_POS_TOPK; ++it) {
    float v = val; int i = n;
    argmax64(v, i);
    if ((threadIdx.x & 63) == 0) { swv[wid] = v; swi[wid] = i; }
    __syncthreads();
    float bv = swv[0]; int bi = swi[0];
    #pragma unroll
    for (int w = 1; w < 4; ++w) {
      if (swv[w] > bv || (swv[w] == bv && swi[w] < bi)) { bv = swv[w]; bi = swi[w]; }
    }
    if (threadIdx.x == 0) { selv[it] = bv; seli[it] = bi; }
    if (n == bi) val = -1.0f;   // remove winner
    __syncthreads();
  }
  if (threadIdx.x < MIN_POS_TOPK) {
    size_t co = ((size_t)b * 256 + blk) * MIN_POS_TOPK + threadIdx.x;
    cand_val[co] = selv[threadIdx.x];
    cand_idx[co] = seli[threadIdx.x];
  }
  if (threadIdx.x == 0) {
    if (s_pos) atomicAdd(&pos_cnt[b], s_pos);
    if (s_neg) atomicAdd(&neg_cnt[b], s_neg);
  }
}

// ---------- K2: merge 2560 candidates -> exact top-10 per image ----------
#define NCAND (256 * MIN_POS_TOPK)
__global__ __launch_bounds__(256)
void k_top10r(const float* __restrict__ cand_val, const int* __restrict__ cand_idx,
              const int* __restrict__ pos_cnt,
              int* __restrict__ num_pos, int* __restrict__ use_fb,
              int* __restrict__ top10) {
  int b = blockIdx.x;
  __shared__ float cv[NCAND];
  __shared__ int   ci[NCAND];
  __shared__ float swv[4];
  __shared__ int   swi[4];
  __shared__ int   sel[MIN_POS_TOPK];
  for (int j = threadIdx.x; j < NCAND; j += 256) {
    cv[j] = cand_val[(size_t)b * NCAND + j];
    ci[j] = cand_idx[(size_t)b * NCAND + j];
  }
  __syncthreads();
  int wid = threadIdx.x >> 6;
  for (int it = 0; it < MIN_POS_TOPK; ++it) {
    float v = -2.0f; int i = INT_MAX;
    for (int j = threadIdx.x; j < NCAND; j += 256) {
      if (cv[j] > v || (cv[j] == v && ci[j] < i)) { v = cv[j]; i = ci[j]; }
    }
    argmax64(v, i);
    if ((threadIdx.x & 63) == 0) { swv[wid] = v; swi[wid] = i; }
    __syncthreads();
    float bv = swv[0]; int bi = swi[0];
    #pragma unroll
    for (int w = 1; w < 4; ++w) {
      if (swv[w] > bv || (swv[w] == bv && swi[w] < bi)) { bv = swv[w]; bi = swi[w]; }
    }
    if (threadIdx.x == 0) sel[it] = bi;
    // remove winner (anchor indices are unique across candidates)
    for (int j = threadIdx.x; j < NCAND; j += 256) {
      if (ci[j] == bi) cv[j] = -2.0f;
    }
    __syncthreads();
  }
  if (threadIdx.x < MIN_POS_TOPK) top10[b * MIN_POS_TOPK + threadIdx.x] = sel[threadIdx.x];
  if (threadIdx.x == 0) {
    int pc = pos_cnt[b];
    int fb = (pc < MIN_POS_TOPK) ? 1 : 0;
    use_fb[b] = fb;
    num_pos[b] = fb ? MIN_POS_TOPK : pc;
  }
}

// ---------- K3: pick the 16-bit bucket containing the k-th smallest neg score ----------
__global__ __launch_bounds__(256)
void k_bucket(const unsigned* __restrict__ hist,
              const int* __restrict__ num_pos, const int* __restrict__ neg_cnt,
              int* __restrict__ subsample, int* __restrict__ bucket,
              int* __restrict__ below, int* __restrict__ total_samples) {
  int b = blockIdx.x;
  int np = num_pos[b];
  int nc = neg_cnt[b];
  int k = NEG_POS_RATIO * np;
  if (nc <= k) {
    if (threadIdx.x == 0) {
      subsample[b] = 0;
      bucket[b] = -1;
      below[b] = 0;
      total_samples[b] = np + nc;
    }
    return;
  }
  const unsigned* h = hist + (size_t)b * NBINS;
  __shared__ unsigned psum[256];
  unsigned s = 0;
  int seg0 = threadIdx.x * 256;
  for (int j = 0; j < 256; ++j) s += h[seg0 + j];
  psum[threadIdx.x] = s;
  __syncthreads();
  if (threadIdx.x == 0) {
    unsigned cum = 0;
    int seg = 255;
    for (int t = 0; t < 256; ++t) {
      if (cum + psum[t] >= (unsigned)k) { seg = t; break; }
      cum += psum[t];
    }
    unsigned c2 = cum;
    int bkt = seg * 256 + 255;
    for (int j = 0; j < 256; ++j) {
      unsigned hv = h[seg * 256 + j];
      if (c2 + hv >= (unsigned)k) { bkt = seg * 256 + j; break; }
      c2 += hv;
    }
    subsample[b] = 1;
    bucket[b] = bkt;
    below[b] = (int)c2;
    total_samples[b] = np + k;
  }
}

// ---------- K4: gather boundary-bucket elements ----------
__global__ __launch_bounds__(256)
void k_gather(const float* __restrict__ miou, const float* __restrict__ scores,
              const int* __restrict__ subsample, const int* __restrict__ bucket,
              unsigned* __restrict__ eqb, int* __restrict__ eqi,
              int* __restrict__ eqcnt) {
  int b = blockIdx.x >> 8;
  if (!subsample[b]) return;
  int n = ((blockIdx.x & 255) << 8) | threadIdx.x;
  int bkt = bucket[b];
  size_t idx = (size_t)b * NANCH + n;
  if (miou[idx] < NEG_THR) {
    unsigned bits = __float_as_uint(scores[idx]);
    if ((int)(bits >> 16) == bkt) {
      int slot = atomicAdd(&eqcnt[b], 1);
      if (slot < EQCAP) {
        eqb[(size_t)b * EQCAP + slot] = bits;
        eqi[(size_t)b * EQCAP + slot] = n;
      }
    }
  }
}

// ---------- K5: rank within bucket -> exact cut (vbits, idx_cut) ----------
__global__ __launch_bounds__(256)
void k_rank(const unsigned* __restrict__ eqb, const int* __restrict__ eqi,
            const int* __restrict__ eqcnt, const int* __restrict__ subsample,
            const int* __restrict__ num_pos, const int* __restrict__ below,
            unsigned* __restrict__ vbits_out, int* __restrict__ idx_cut) {
  int b = blockIdx.x;
  if (!subsample[b]) {
    if (threadIdx.x == 0) { vbits_out[b] = 0u; idx_cut[b] = -1; }
    return;
  }
  int E = eqcnt[b]; if (E > EQCAP) E = EQCAP;
  int r = NEG_POS_RATIO * num_pos[b] - below[b];   // 1-based rank within bucket
  __shared__ unsigned sb_[EQCAP];
  __shared__ int      si_[EQCAP];
  for (int j = threadIdx.x; j < E; j += 256) {
    sb_[j] = eqb[(size_t)b * EQCAP + j];
    si_[j] = eqi[(size_t)b * EQCAP + j];
  }
  __syncthreads();
  for (int e = threadIdx.x; e < E; e += 256) {
    unsigned mb = sb_[e]; int mi = si_[e];
    int rank = 0;
    for (int j = 0; j < E; ++j) {
      unsigned ob = sb_[j]; int oi = si_[j];
      rank += (ob < mb || (ob == mb && oi < mi)) ? 1 : 0;
    }
    if (rank == r - 1) { vbits_out[b] = mb; idx_cut[b] = mi; }
  }
}

// ---------- K6: per-anchor loss accumulation ----------
__global__ __launch_bounds__(256)
void k_loss(const float* __restrict__ cls, const float* __restrict__ reg,
            const float* __restrict__ anchors, const float* __restrict__ tb,
            const int* __restrict__ tl, const float* __restrict__ scores,
            const float* __restrict__ miou, const int* __restrict__ midx,
            const int* __restrict__ use_fb, const int* __restrict__ top10,
            const int* __restrict__ subsample, const unsigned* __restrict__ vbits,
            const int* __restrict__ idx_cut,
            float* __restrict__ sums /* [NB][3] : pos, neg, reg */) {
  int b = blockIdx.x >> 8;
  int n = ((blockIdx.x & 255) << 8) | threadIdx.x;
  __shared__ int s_top10[MIN_POS_TOPK];
  __shared__ int s_usefb, s_sub, s_cut;
  __shared__ unsigned s_vb;
  __shared__ float accp, accn, accr;
  if (threadIdx.x < MIN_POS_TOPK) s_top10[threadIdx.x] = top10[b * MIN_POS_TOPK + threadIdx.x];
  if (threadIdx.x == 0) {
    s_usefb = use_fb[b]; s_sub = subsample[b]; s_cut = idx_cut[b]; s_vb = vbits[b];
    accp = 0.0f; accn = 0.0f; accr = 0.0f;
  }
  __syncthreads();

  size_t idx = (size_t)b * NANCH + n;
  float mi = miou[idx];
  int mx = midx[idx];

  bool pos;
  if (s_usefb) {
    pos = false;
    #pragma unroll
    for (int i = 0; i < MIN_POS_TOPK; ++i) pos |= (s_top10[i] == n);
  } else {
    pos = (mi >= POS_THR);
  }
  bool neg = (mi < NEG_THR);
  bool nsel = false;
  if (neg) {
    if (!s_sub) nsel = true;
    else {
      unsigned sb = __float_as_uint(scores[idx]);
      nsel = (sb < s_vb) || (sb == s_vb && n <= s_cut);
    }
  }

  float cp = 0.0f, cn = 0.0f, rg = 0.0f;
  if (pos || nsel) {
    int t = 0;
    if (pos) t = tl[b * NM + mx];
    size_t cb = ((size_t)b * NC) * NANCH + n;
    float mxl = -3.0e38f, l0 = 0.0f, lt = 0.0f;
    for (int c = 0; c < NC; ++c) {
      float l = cls[cb + (size_t)c * NANCH];
      if (c == 0) l0 = l;
      if (c == t) lt = l;
      mxl = fmaxf(mxl, l);
    }
    float se = 0.0f;
    for (int c = 0; c < NC; ++c) {
      float l = cls[cb + (size_t)c * NANCH];
      se += expf(l - mxl);
    }
    float lse = mxl + logf(se);
    if (nsel) {
      float ce = lse - l0;
      float pt = expf(-ce);
      float om = 1.0f - pt;
      cn = F_ALPHA * om * om * ce;
    }
    if (pos) {
      float ce = lse - lt;
      float pt = expf(-ce);
      float om = 1.0f - pt;
      cp = F_ALPHA * om * om * ce;
      float d[4];
      decode_box(anchors, reg, b, n, d);
      const float* g = tb + ((size_t)b * NM + mx) * 4;
      float gx1 = g[0], gy1 = g[1], gx2 = g[2], gy2 = g[3];
      float area_a = (d[2] - d[0]) * (d[3] - d[1]);
      float area_b = (gx2 - gx1) * (gy2 - gy1);
      float lx = fmaxf(d[0], gx1), ly = fmaxf(d[1], gy1);
      float rx = fminf(d[2], gx2), ry = fminf(d[3], gy2);
      float iw = fmaxf(rx - lx, 0.0f), ih = fmaxf(ry - ly, 0.0f);
      float inter = iw * ih;
      float uni = area_a + area_b - inter;
      float iou = inter / fmaxf(uni, 1e-7f);
      float ex1 = fminf(d[0], gx1), ey1 = fminf(d[1], gy1);
      float ex2 = fmaxf(d[2], gx2), ey2 = fmaxf(d[3], gy2);
      float ew = fmaxf(ex2 - ex1, 0.0f), eh = fmaxf(ey2 - ey1, 0.0f);
      float enc = ew * eh;
      float giou = iou - (enc - uni) / fmaxf(enc, 1e-7f);
      rg = 1.0f - giou;
    }
  }

  if (cp != 0.0f) atomicAdd(&accp, cp);
  if (cn != 0.0f) atomicAdd(&accn, cn);
  if (rg != 0.0f) atomicAdd(&accr, rg);
  __syncthreads();
  if (threadIdx.x == 0) {
    if (accp != 0.0f) atomicAdd(&sums[b * 3 + 0], accp);
    if (accn != 0.0f) atomicAdd(&sums[b * 3 + 1], accn);
    if (accr != 0.0f) atomicAdd(&sums[b * 3 + 2], accr);
  }
}

// ---------- K7: finalize ----------
__global__ void k_final(const float* __restrict__ sums,
                        const int* __restrict__ total_samples,
                        const int* __restrict__ num_pos,
                        float* __restrict__ out) {
  if (threadIdx.x == 0 && blockIdx.x == 0) {
    float cm = 0.0f, rm = 0.0f;
    for (int b = 0; b < NB; ++b) {
      int ts = total_samples[b]; if (ts < 1) ts = 1;
      int np = num_pos[b]; if (np < 1) np = 1;
      cm += (sums[b * 3 + 0] + sums[b * 3 + 1]) / (float)ts;
      rm += sums[b * 3 + 2] / (float)np;
    }
    out[0] = cm / (float)NB + rm / (float)NB;
  }
}

extern "C" void kernel_launch(void* const* d_in, const int* in_sizes, int n_in,
                              void* d_out, int out_size, void* d_ws, size_t ws_size,
                              hipStream_t stream) {
  const float* cls     = (const float*)d_in[0];
  const float* reg     = (const float*)d_in[1];
  const float* anchors = (const float*)d_in[2];
  const float* tb      = (const float*)d_in[3];
  const int*   tl      = (const int*)d_in[4];
  const float* scores  = (const float*)d_in[5];
  float* out = (float*)d_out;

  char* ws = (char*)d_ws;
  size_t off = 0;
  float* miou = (float*)(ws + off);            off += (size_t)4 * NB * NANCH;
  int*   midx = (int*)(ws + off);              off += (size_t)4 * NB * NANCH;
  unsigned* hist = (unsigned*)(ws + off);      off += (size_t)4 * NB * NBINS;
  float* cand_val = (float*)(ws + off);        off += (size_t)4 * NB * NCAND;
  int*   cand_idx = (int*)(ws + off);          off += (size_t)4 * NB * NCAND;
  unsigned* eqb = (unsigned*)(ws + off);       off += (size_t)4 * NB * EQCAP;
  int*   eqi = (int*)(ws + off);               off += (size_t)4 * NB * EQCAP;
  int* scal = (int*)(ws + off);
  int* pos_cnt       = scal;
  int* neg_cnt       = scal + NB;
  int* num_pos       = scal + 2 * NB;
  int* use_fb        = scal + 3 * NB;
  int* subsample     = scal + 4 * NB;
  int* idx_cut       = scal + 5 * NB;
  unsigned* vbits    = (unsigned*)(scal + 6 * NB);
  int* total_samples = scal + 7 * NB;
  int* bucket        = scal + 8 * NB;
  int* below         = scal + 9 * NB;
  int* eqcnt         = scal + 10 * NB;
  int* top10         = scal + 11 * NB;                         // NB*10
  float* sums        = (float*)(scal + 11 * NB + MIN_POS_TOPK * NB); // NB*3

  k_init<<<1024, 256, 0, stream>>>(hist, pos_cnt, neg_cnt, eqcnt, sums);
  k_iou<<<NB * 256, 256, 0, stream>>>(reg, anchors, tb, scores, miou, midx,
                                      pos_cnt, neg_cnt, hist, cand_val, cand_idx);
  k_top10r<<<NB, 256, 0, stream>>>(cand_val, cand_idx, pos_cnt, num_pos, use_fb, top10);
  k_bucket<<<NB, 256, 0, stream>>>(hist, num_pos, neg_cnt, subsample, bucket,
                                   below, total_samples);
  k_gather<<<NB * 256, 256, 0, stream>>>(miou, scores, subsample, bucket,
                                         eqb, eqi, eqcnt);
  k_rank<<<NB, 256, 0, stream>>>(eqb, eqi, eqcnt, subsample, num_pos, below,
                                 vbits, idx_cut);
  k_loss<<<NB * 256, 256, 0, stream>>>(cls, reg, anchors, tb, tl, scores,
                                       miou, midx, use_fb, top10, subsample,
                                       vbits, idx_cut, sums);
  k_final<<<1, 1, 0, stream>>>(sums, total_samples, num_pos, out);
}

// Round 4
// 151.171 us; speedup vs baseline: 7.9182x; 1.1778x over previous
//
#include <hip/hip_runtime.h>
#include <math.h>
#include <limits.h>

#define NB 16
#define NC 21
#define NANCH 65536
#define NM 20

#define POS_THR 0.5f
#define NEG_THR 0.4f
#define F_ALPHA 0.25f
#define MIN_POS_TOPK 10
#define NEG_POS_RATIO 3

#define NBINS 65536
#define EQCAP 2048
#define APT 4          // anchors per thread in k_iou
#define NCAND (256 * MIN_POS_TOPK)

// wave(64)-wide argmax of (v desc, i asc)
__device__ __forceinline__ void argmax64(float& v, int& i) {
  #pragma unroll
  for (int m = 32; m >= 1; m >>= 1) {
    float ov = __shfl_xor(v, m, 64);
    int   oi = __shfl_xor(i, m, 64);
    if (ov > v || (ov == v && oi < i)) { v = ov; i = oi; }
  }
}

// ---------- K0: zero hist + scalar accumulators ----------
__global__ void k_init(unsigned* hist, int* pos_cnt, int* neg_cnt,
                       int* eqcnt, float* sums) {
  size_t tid = (size_t)blockIdx.x * blockDim.x + threadIdx.x;
  size_t tot = (size_t)NB * NBINS;
  for (size_t j = tid; j < tot; j += (size_t)gridDim.x * blockDim.x) hist[j] = 0u;
  if (blockIdx.x == 0) {
    int t = threadIdx.x;
    if (t < NB) { pos_cnt[t] = 0; neg_cnt[t] = 0; eqcnt[t] = 0; }
    if (t < 3 * NB) sums[t] = 0.0f;
  }
}

// ---------- K1: decode + IoU max/argmax + counts + score hist + wave top-10 ----------
__global__ __launch_bounds__(256)
void k_iou(const float* __restrict__ reg, const float* __restrict__ anchors,
           const float* __restrict__ tb, const float* __restrict__ scores,
           float* __restrict__ miou, int* __restrict__ midx,
           int* __restrict__ pos_cnt, int* __restrict__ neg_cnt,
           unsigned* __restrict__ hist,
           float* __restrict__ cand_val, int* __restrict__ cand_idx) {
  __shared__ float4 tbs4[NM];
  __shared__ float  tarea[NM];
  int b   = blockIdx.x >> 6;           // 64 blocks per image
  int blk = blockIdx.x & 63;
  int n0  = (blk << 10) + threadIdx.x; // 1024 anchors per block
  if (threadIdx.x < NM) {
    float4 t4 = ((const float4*)tb)[b * NM + threadIdx.x];
    tbs4[threadIdx.x] = t4;
    tarea[threadIdx.x] = (t4.z - t4.x) * (t4.w - t4.y);
  }
  __syncthreads();

  // ---- decode 4 anchors ----
  float dv[APT][4];
  float areaA[APT];
  #pragma unroll
  for (int j = 0; j < APT; ++j) {
    int n = n0 + j * 256;
    float4 a4 = ((const float4*)anchors)[n];
    float aw = a4.z - a4.x, ah = a4.w - a4.y;
    float acx = a4.x + 0.5f * aw, acy = a4.y + 0.5f * ah;
    size_t rb = ((size_t)b * 4) * NANCH + n;
    float rx = reg[rb];
    float ry = reg[rb + (size_t)NANCH];
    float rw = reg[rb + 2 * (size_t)NANCH];
    float rh = reg[rb + 3 * (size_t)NANCH];
    float cx = acx + rx * aw, cy = acy + ry * ah;
    float w = aw * expf(rw), h = ah * expf(rh);
    dv[j][0] = cx - 0.5f * w;
    dv[j][1] = cy - 0.5f * h;
    dv[j][2] = cx + 0.5f * w;
    dv[j][3] = cy + 0.5f * h;
    areaA[j] = (dv[j][2] - dv[j][0]) * (dv[j][3] - dv[j][1]);
  }

  // ---- cross-mult argmax over 20 boxes (m outer, anchors inner) ----
  float bI[APT], bU[APT];
  int   bM[APT];
  {
    float4 t = tbs4[0];
    float ab = tarea[0];
    #pragma unroll
    for (int j = 0; j < APT; ++j) {
      float lx = fmaxf(dv[j][0], t.x), ly = fmaxf(dv[j][1], t.y);
      float rx2 = fminf(dv[j][2], t.z), ry2 = fminf(dv[j][3], t.w);
      float iw = fmaxf(rx2 - lx, 0.0f), ih = fmaxf(ry2 - ly, 0.0f);
      float inter = iw * ih;
      bI[j] = inter;
      bU[j] = areaA[j] + ab - inter;
      bM[j] = 0;
    }
  }
  #pragma unroll
  for (int m = 1; m < NM; ++m) {
    float4 t = tbs4[m];
    float ab = tarea[m];
    #pragma unroll
    for (int j = 0; j < APT; ++j) {
      float lx = fmaxf(dv[j][0], t.x), ly = fmaxf(dv[j][1], t.y);
      float rx2 = fminf(dv[j][2], t.z), ry2 = fminf(dv[j][3], t.w);
      float iw = fmaxf(rx2 - lx, 0.0f), ih = fmaxf(ry2 - ly, 0.0f);
      float inter = iw * ih;
      float uni = areaA[j] + ab - inter;
      // inter/uni > bI/bU  <=>  inter*bU > bI*uni  (both unions > 0)
      if (inter * bU[j] > bI[j] * uni) { bI[j] = inter; bU[j] = uni; bM[j] = m; }
    }
  }

  // ---- finalize miou/midx, counts, hist ----
  float tv[APT];
  int   ti[APT];
  int cp = 0, cn = 0;
  #pragma unroll
  for (int j = 0; j < APT; ++j) {
    int n = n0 + j * 256;
    size_t idx = (size_t)b * NANCH + n;
    float q = bI[j] / fmaxf(bU[j], 1e-7f);   // IEEE, matches reference
    miou[idx] = q;
    midx[idx] = bM[j];
    tv[j] = q;
    ti[j] = n;
    bool p  = (q >= POS_THR);
    bool ng = (q < NEG_THR);
    cp += __popcll(__ballot(p));
    cn += __popcll(__ballot(ng));
    float sc = scores[idx];
    if (ng) {
      unsigned bits = __float_as_uint(sc);
      atomicAdd(&hist[(size_t)b * NBINS + (bits >> 16)], 1u);
    }
  }
  int lane = threadIdx.x & 63;
  if (lane == 0) {
    if (cp) atomicAdd(&pos_cnt[b], cp);
    if (cn) atomicAdd(&neg_cnt[b], cn);
  }

  // ---- barrier-free wave top-10 over the wave's 256 anchors ----
  int wid = threadIdx.x >> 6;
  size_t coff = ((size_t)(b * 64 + blk) * 4 + wid) * MIN_POS_TOPK;
  for (int it = 0; it < MIN_POS_TOPK; ++it) {
    float mv = tv[0]; int mi_ = ti[0];
    #pragma unroll
    for (int j = 1; j < APT; ++j) {
      if (tv[j] > mv || (tv[j] == mv && ti[j] < mi_)) { mv = tv[j]; mi_ = ti[j]; }
    }
    argmax64(mv, mi_);
    if (lane == 0) { cand_val[coff + it] = mv; cand_idx[coff + it] = mi_; }
    #pragma unroll
    for (int j = 0; j < APT; ++j) {
      if (ti[j] == mi_) tv[j] = -2.0f;
    }
  }
}

// ---------- K2 (fused): blocks 0..15 top-10 merge, blocks 16..31 bucket pick ----------
__global__ __launch_bounds__(256)
void k_mid(const float* __restrict__ cand_val, const int* __restrict__ cand_idx,
           const unsigned* __restrict__ hist,
           const int* __restrict__ pos_cnt, const int* __restrict__ neg_cnt,
           int* __restrict__ num_pos, int* __restrict__ use_fb,
           int* __restrict__ top10,
           int* __restrict__ subsample, int* __restrict__ bucket,
           int* __restrict__ below, int* __restrict__ total_samples) {
  if (blockIdx.x < NB) {
    // ---- top-10 merge over 2560 candidates ----
    int b = blockIdx.x;
    __shared__ float cv[NCAND];
    __shared__ int   ci[NCAND];
    __shared__ float swv[4];
    __shared__ int   swi[4];
    __shared__ int   sel[MIN_POS_TOPK];
    for (int j = threadIdx.x; j < NCAND; j += 256) {
      cv[j] = cand_val[(size_t)b * NCAND + j];
      ci[j] = cand_idx[(size_t)b * NCAND + j];
    }
    __syncthreads();
    int wid = threadIdx.x >> 6;
    for (int it = 0; it < MIN_POS_TOPK; ++it) {
      float v = -2.0f; int i = INT_MAX;
      for (int j = threadIdx.x; j < NCAND; j += 256) {
        if (cv[j] > v || (cv[j] == v && ci[j] < i)) { v = cv[j]; i = ci[j]; }
      }
      argmax64(v, i);
      if ((threadIdx.x & 63) == 0) { swv[wid] = v; swi[wid] = i; }
      __syncthreads();
      float bv = swv[0]; int bi = swi[0];
      #pragma unroll
      for (int w = 1; w < 4; ++w) {
        if (swv[w] > bv || (swv[w] == bv && swi[w] < bi)) { bv = swv[w]; bi = swi[w]; }
      }
      if (threadIdx.x == 0) sel[it] = bi;
      for (int j = threadIdx.x; j < NCAND; j += 256) {
        if (ci[j] == bi) cv[j] = -2.0f;
      }
      __syncthreads();
    }
    if (threadIdx.x < MIN_POS_TOPK) top10[b * MIN_POS_TOPK + threadIdx.x] = sel[threadIdx.x];
    if (threadIdx.x == 0) {
      int pc = pos_cnt[b];
      int fb = (pc < MIN_POS_TOPK) ? 1 : 0;
      use_fb[b] = fb;
      num_pos[b] = fb ? MIN_POS_TOPK : pc;
    }
  } else {
    // ---- bucket pick for negative subsampling ----
    int b = blockIdx.x - NB;
    int pc = pos_cnt[b];
    int np = (pc < MIN_POS_TOPK) ? MIN_POS_TOPK : pc;
    int nc = neg_cnt[b];
    int k = NEG_POS_RATIO * np;
    if (nc <= k) {
      if (threadIdx.x == 0) {
        subsample[b] = 0;
        bucket[b] = -1;
        below[b] = 0;
        total_samples[b] = np + nc;
      }
      return;
    }
    const unsigned* h = hist + (size_t)b * NBINS;
    __shared__ unsigned psum[256];
    unsigned s = 0;
    int seg0 = threadIdx.x * 256;
    for (int j = 0; j < 256; ++j) s += h[seg0 + j];
    psum[threadIdx.x] = s;
    __syncthreads();
    if (threadIdx.x == 0) {
      unsigned cum = 0;
      int seg = 255;
      for (int t = 0; t < 256; ++t) {
        if (cum + psum[t] >= (unsigned)k) { seg = t; break; }
        cum += psum[t];
      }
      unsigned c2 = cum;
      int bkt = seg * 256 + 255;
      for (int j = 0; j < 256; ++j) {
        unsigned hv = h[seg * 256 + j];
        if (c2 + hv >= (unsigned)k) { bkt = seg * 256 + j; break; }
        c2 += hv;
      }
      subsample[b] = 1;
      bucket[b] = bkt;
      below[b] = (int)c2;
      total_samples[b] = np + k;
    }
  }
}

// ---------- K3: gather boundary-bucket elements ----------
__global__ __launch_bounds__(256)
void k_gather(const float* __restrict__ miou, const float* __restrict__ scores,
              const int* __restrict__ subsample, const int* __restrict__ bucket,
              unsigned* __restrict__ eqb, int* __restrict__ eqi,
              int* __restrict__ eqcnt) {
  int b = blockIdx.x >> 8;
  if (!subsample[b]) return;
  int n = ((blockIdx.x & 255) << 8) | threadIdx.x;
  int bkt = bucket[b];
  size_t idx = (size_t)b * NANCH + n;
  if (miou[idx] < NEG_THR) {
    unsigned bits = __float_as_uint(scores[idx]);
    if ((int)(bits >> 16) == bkt) {
      int slot = atomicAdd(&eqcnt[b], 1);
      if (slot < EQCAP) {
        eqb[(size_t)b * EQCAP + slot] = bits;
        eqi[(size_t)b * EQCAP + slot] = n;
      }
    }
  }
}

// ---------- K4: rank within bucket -> exact cut (vbits, idx_cut) ----------
__global__ __launch_bounds__(256)
void k_rank(const unsigned* __restrict__ eqb, const int* __restrict__ eqi,
            const int* __restrict__ eqcnt, const int* __restrict__ subsample,
            const int* __restrict__ num_pos, const int* __restrict__ below,
            unsigned* __restrict__ vbits_out, int* __restrict__ idx_cut) {
  int b = blockIdx.x;
  if (!subsample[b]) {
    if (threadIdx.x == 0) { vbits_out[b] = 0u; idx_cut[b] = -1; }
    return;
  }
  int E = eqcnt[b]; if (E > EQCAP) E = EQCAP;
  int r = NEG_POS_RATIO * num_pos[b] - below[b];   // 1-based rank within bucket
  __shared__ unsigned sb_[EQCAP];
  __shared__ int      si_[EQCAP];
  for (int j = threadIdx.x; j < E; j += 256) {
    sb_[j] = eqb[(size_t)b * EQCAP + j];
    si_[j] = eqi[(size_t)b * EQCAP + j];
  }
  __syncthreads();
  for (int e = threadIdx.x; e < E; e += 256) {
    unsigned mb = sb_[e]; int mi = si_[e];
    int rank = 0;
    for (int j = 0; j < E; ++j) {
      unsigned ob = sb_[j]; int oi = si_[j];
      rank += (ob < mb || (ob == mb && oi < mi)) ? 1 : 0;
    }
    if (rank == r - 1) { vbits_out[b] = mb; idx_cut[b] = mi; }
  }
}

// ---------- K5: per-anchor loss accumulation ----------
__global__ __launch_bounds__(256)
void k_loss(const float* __restrict__ cls, const float* __restrict__ reg,
            const float* __restrict__ anchors, const float* __restrict__ tb,
            const int* __restrict__ tl, const float* __restrict__ scores,
            const float* __restrict__ miou, const int* __restrict__ midx,
            const int* __restrict__ use_fb, const int* __restrict__ top10,
            const int* __restrict__ subsample, const unsigned* __restrict__ vbits,
            const int* __restrict__ idx_cut,
            float* __restrict__ sums /* [NB][3] : pos, neg, reg */) {
  int b = blockIdx.x >> 8;
  int n = ((blockIdx.x & 255) << 8) | threadIdx.x;
  __shared__ int s_top10[MIN_POS_TOPK];
  __shared__ int s_usefb, s_sub, s_cut;
  __shared__ unsigned s_vb;
  __shared__ float accp, accn, accr;
  if (threadIdx.x < MIN_POS_TOPK) s_top10[threadIdx.x] = top10[b * MIN_POS_TOPK + threadIdx.x];
  if (threadIdx.x == 0) {
    s_usefb = use_fb[b]; s_sub = subsample[b]; s_cut = idx_cut[b]; s_vb = vbits[b];
    accp = 0.0f; accn = 0.0f; accr = 0.0f;
  }
  __syncthreads();

  size_t idx = (size_t)b * NANCH + n;
  float mi = miou[idx];

  bool pos;
  if (s_usefb) {
    pos = false;
    #pragma unroll
    for (int i = 0; i < MIN_POS_TOPK; ++i) pos |= (s_top10[i] == n);
  } else {
    pos = (mi >= POS_THR);
  }
  bool neg = (mi < NEG_THR);
  bool nsel = false;
  if (neg) {
    if (!s_sub) nsel = true;
    else {
      unsigned sb = __float_as_uint(scores[idx]);
      nsel = (sb < s_vb) || (sb == s_vb && n <= s_cut);
    }
  }

  float cp = 0.0f, cn = 0.0f, rg = 0.0f;
  if (pos || nsel) {
    int mx = 0, t = 0;
    if (pos) { mx = midx[idx]; t = tl[b * NM + mx]; }
    size_t cb = ((size_t)b * NC) * NANCH + n;
    float mxl = -3.0e38f, l0 = 0.0f, lt = 0.0f;
    for (int c = 0; c < NC; ++c) {
      float l = cls[cb + (size_t)c * NANCH];
      if (c == 0) l0 = l;
      if (c == t) lt = l;
      mxl = fmaxf(mxl, l);
    }
    float se = 0.0f;
    for (int c = 0; c < NC; ++c) {
      float l = cls[cb + (size_t)c * NANCH];
      se += expf(l - mxl);
    }
    float lse = mxl + logf(se);
    if (nsel) {
      float ce = lse - l0;
      float pt = expf(-ce);
      float om = 1.0f - pt;
      cn = F_ALPHA * om * om * ce;
    }
    if (pos) {
      float ce = lse - lt;
      float pt = expf(-ce);
      float om = 1.0f - pt;
      cp = F_ALPHA * om * om * ce;
      // decode + GIoU vs matched GT
      const float4 a4 = ((const float4*)anchors)[n];
      float aw = a4.z - a4.x, ah = a4.w - a4.y;
      float acx = a4.x + 0.5f * aw, acy = a4.y + 0.5f * ah;
      size_t rb = ((size_t)b * 4) * NANCH + n;
      float rx = reg[rb];
      float ry = reg[rb + (size_t)NANCH];
      float rw = reg[rb + 2 * (size_t)NANCH];
      float rh = reg[rb + 3 * (size_t)NANCH];
      float ccx = acx + rx * aw, ccy = acy + ry * ah;
      float w = aw * expf(rw), h = ah * expf(rh);
      float d0 = ccx - 0.5f * w, d1 = ccy - 0.5f * h;
      float d2 = ccx + 0.5f * w, d3 = ccy + 0.5f * h;
      const float* g = tb + ((size_t)b * NM + mx) * 4;
      float gx1 = g[0], gy1 = g[1], gx2 = g[2], gy2 = g[3];
      float area_a = (d2 - d0) * (d3 - d1);
      float area_b = (gx2 - gx1) * (gy2 - gy1);
      float lx = fmaxf(d0, gx1), ly = fmaxf(d1, gy1);
      float rx2 = fminf(d2, gx2), ry2 = fminf(d3, gy2);
      float iw = fmaxf(rx2 - lx, 0.0f), ih = fmaxf(ry2 - ly, 0.0f);
      float inter = iw * ih;
      float uni = area_a + area_b - inter;
      float iou = inter / fmaxf(uni, 1e-7f);
      float ex1 = fminf(d0, gx1), ey1 = fminf(d1, gy1);
      float ex2 = fmaxf(d2, gx2), ey2 = fmaxf(d3, gy2);
      float ew = fmaxf(ex2 - ex1, 0.0f), eh = fmaxf(ey2 - ey1, 0.0f);
      float enc = ew * eh;
      float giou = iou - (enc - uni) / fmaxf(enc, 1e-7f);
      rg = 1.0f - giou;
    }
  }

  if (cp != 0.0f) atomicAdd(&accp, cp);
  if (cn != 0.0f) atomicAdd(&accn, cn);
  if (rg != 0.0f) atomicAdd(&accr, rg);
  __syncthreads();
  if (threadIdx.x == 0) {
    if (accp != 0.0f) atomicAdd(&sums[b * 3 + 0], accp);
    if (accn != 0.0f) atomicAdd(&sums[b * 3 + 1], accn);
    if (accr != 0.0f) atomicAdd(&sums[b * 3 + 2], accr);
  }
}

// ---------- K6: finalize ----------
__global__ void k_final(const float* __restrict__ sums,
                        const int* __restrict__ total_samples,
                        const int* __restrict__ num_pos,
                        float* __restrict__ out) {
  if (threadIdx.x == 0 && blockIdx.x == 0) {
    float cm = 0.0f, rm = 0.0f;
    for (int b = 0; b < NB; ++b) {
      int ts = total_samples[b]; if (ts < 1) ts = 1;
      int np = num_pos[b]; if (np < 1) np = 1;
      cm += (sums[b * 3 + 0] + sums[b * 3 + 1]) / (float)ts;
      rm += sums[b * 3 + 2] / (float)np;
    }
    out[0] = cm / (float)NB + rm / (float)NB;
  }
}

extern "C" void kernel_launch(void* const* d_in, const int* in_sizes, int n_in,
                              void* d_out, int out_size, void* d_ws, size_t ws_size,
                              hipStream_t stream) {
  const float* cls     = (const float*)d_in[0];
  const float* reg     = (const float*)d_in[1];
  const float* anchors = (const float*)d_in[2];
  const float* tb      = (const float*)d_in[3];
  const int*   tl      = (const int*)d_in[4];
  const float* scores  = (const float*)d_in[5];
  float* out = (float*)d_out;

  char* ws = (char*)d_ws;
  size_t off = 0;
  float* miou = (float*)(ws + off);            off += (size_t)4 * NB * NANCH;
  int*   midx = (int*)(ws + off);              off += (size_t)4 * NB * NANCH;
  unsigned* hist = (unsigned*)(ws + off);      off += (size_t)4 * NB * NBINS;
  float* cand_val = (float*)(ws + off);        off += (size_t)4 * NB * NCAND;
  int*   cand_idx = (int*)(ws + off);          off += (size_t)4 * NB * NCAND;
  unsigned* eqb = (unsigned*)(ws + off);       off += (size_t)4 * NB * EQCAP;
  int*   eqi = (int*)(ws + off);               off += (size_t)4 * NB * EQCAP;
  int* scal = (int*)(ws + off);
  int* pos_cnt       = scal;
  int* neg_cnt       = scal + NB;
  int* num_pos       = scal + 2 * NB;
  int* use_fb        = scal + 3 * NB;
  int* subsample     = scal + 4 * NB;
  int* idx_cut       = scal + 5 * NB;
  unsigned* vbits    = (unsigned*)(scal + 6 * NB);
  int* total_samples = scal + 7 * NB;
  int* bucket        = scal + 8 * NB;
  int* below         = scal + 9 * NB;
  int* eqcnt         = scal + 10 * NB;
  int* top10         = scal + 11 * NB;                         // NB*10
  float* sums        = (float*)(scal + 11 * NB + MIN_POS_TOPK * NB); // NB*3

  k_init<<<1024, 256, 0, stream>>>(hist, pos_cnt, neg_cnt, eqcnt, sums);
  k_iou<<<NB * 64, 256, 0, stream>>>(reg, anchors, tb, scores, miou, midx,
                                     pos_cnt, neg_cnt, hist, cand_val, cand_idx);
  k_mid<<<2 * NB, 256, 0, stream>>>(cand_val, cand_idx, hist, pos_cnt, neg_cnt,
                                    num_pos, use_fb, top10,
                                    subsample, bucket, below, total_samples);
  k_gather<<<NB * 256, 256, 0, stream>>>(miou, scores, subsample, bucket,
                                         eqb, eqi, eqcnt);
  k_rank<<<NB, 256, 0, stream>>>(eqb, eqi, eqcnt, subsample, num_pos, below,
                                 vbits, idx_cut);
  k_loss<<<NB * 256, 256, 0, stream>>>(cls, reg, anchors, tb, tl, scores,
                                       miou, midx, use_fb, top10, subsample,
                                       vbits, idx_cut, sums);
  k_final<<<1, 1, 0, stream>>>(sums, total_samples, num_pos, out);
}

// Round 7
// 139.406 us; speedup vs baseline: 8.5865x; 1.0844x over previous
//
#include <hip/hip_runtime.h>
#include <math.h>
#include <limits.h>

#define NB 16
#define NC 21
#define NANCH 65536
#define NM 20

#define POS_THR 0.5f
#define NEG_THR 0.4f
#define F_ALPHA 0.25f
#define MIN_POS_TOPK 10
#define NEG_POS_RATIO 3

#define NBINS 16384          // value bins: (unsigned)(score * 16384.0f), exact & monotone
#define SEGSZ (NBINS / 256)  // 64 bins per thread in the bucket scan
#define EQCAP 2048
#define APT 4                // anchors per thread in k_iou
#define NCAND (256 * MIN_POS_TOPK)

// value-based score bin: monotone in float bits for non-negative scores.
// s * 2^14 is exact (exponent shift); unsigned truncation is monotone.
__device__ __forceinline__ unsigned score_bin(float s) {
  unsigned b = (unsigned)(s * 16384.0f);
  return b > (NBINS - 1) ? (NBINS - 1) : b;
}

// wave(64)-wide argmax of (v desc, i asc)
__device__ __forceinline__ void argmax64(float& v, int& i) {
  #pragma unroll
  for (int m = 32; m >= 1; m >>= 1) {
    float ov = __shfl_xor(v, m, 64);
    int   oi = __shfl_xor(i, m, 64);
    if (ov > v || (ov == v && oi < i)) { v = ov; i = oi; }
  }
}

// ---------- K0: zero hist + scalar accumulators ----------
__global__ void k_init(unsigned* hist, int* pos_cnt, int* neg_cnt,
                       int* eqcnt, float* sums) {
  size_t tid = (size_t)blockIdx.x * blockDim.x + threadIdx.x;
  size_t tot = (size_t)NB * NBINS;
  for (size_t j = tid; j < tot; j += (size_t)gridDim.x * blockDim.x) hist[j] = 0u;
  if (blockIdx.x == 0) {
    int t = threadIdx.x;
    if (t < NB) { pos_cnt[t] = 0; neg_cnt[t] = 0; eqcnt[t] = 0; }
    if (t < 3 * NB) sums[t] = 0.0f;
  }
}

// ---------- K1: decode + IoU max/argmax + counts + score hist + wave top-10 ----------
__global__ __launch_bounds__(256)
void k_iou(const float* __restrict__ reg, const float* __restrict__ anchors,
           const float* __restrict__ tb, const float* __restrict__ scores,
           float* __restrict__ miou, int* __restrict__ midx,
           int* __restrict__ pos_cnt, int* __restrict__ neg_cnt,
           unsigned* __restrict__ hist,
           float* __restrict__ cand_val, int* __restrict__ cand_idx) {
  __shared__ float4 tbs4[NM];
  __shared__ float  tarea[NM];
  int b   = blockIdx.x >> 6;           // 64 blocks per image
  int blk = blockIdx.x & 63;
  int n0  = (blk << 10) + threadIdx.x; // 1024 anchors per block
  if (threadIdx.x < NM) {
    float4 t4 = ((const float4*)tb)[b * NM + threadIdx.x];
    tbs4[threadIdx.x] = t4;
    tarea[threadIdx.x] = (t4.z - t4.x) * (t4.w - t4.y);
  }
  __syncthreads();

  // ---- decode 4 anchors ----
  float dv[APT][4];
  float areaA[APT];
  #pragma unroll
  for (int j = 0; j < APT; ++j) {
    int n = n0 + j * 256;
    float4 a4 = ((const float4*)anchors)[n];
    float aw = a4.z - a4.x, ah = a4.w - a4.y;
    float acx = a4.x + 0.5f * aw, acy = a4.y + 0.5f * ah;
    size_t rb = ((size_t)b * 4) * NANCH + n;
    float rx = reg[rb];
    float ry = reg[rb + (size_t)NANCH];
    float rw = reg[rb + 2 * (size_t)NANCH];
    float rh = reg[rb + 3 * (size_t)NANCH];
    float cx = acx + rx * aw, cy = acy + ry * ah;
    float w = aw * expf(rw), h = ah * expf(rh);
    dv[j][0] = cx - 0.5f * w;
    dv[j][1] = cy - 0.5f * h;
    dv[j][2] = cx + 0.5f * w;
    dv[j][3] = cy + 0.5f * h;
    areaA[j] = (dv[j][2] - dv[j][0]) * (dv[j][3] - dv[j][1]);
  }

  // ---- cross-mult argmax over 20 boxes (m outer, anchors inner) ----
  float bI[APT], bU[APT];
  int   bM[APT];
  {
    float4 t = tbs4[0];
    float ab = tarea[0];
    #pragma unroll
    for (int j = 0; j < APT; ++j) {
      float lx = fmaxf(dv[j][0], t.x), ly = fmaxf(dv[j][1], t.y);
      float rx2 = fminf(dv[j][2], t.z), ry2 = fminf(dv[j][3], t.w);
      float iw = fmaxf(rx2 - lx, 0.0f), ih = fmaxf(ry2 - ly, 0.0f);
      float inter = iw * ih;
      bI[j] = inter;
      bU[j] = areaA[j] + ab - inter;
      bM[j] = 0;
    }
  }
  #pragma unroll
  for (int m = 1; m < NM; ++m) {
    float4 t = tbs4[m];
    float ab = tarea[m];
    #pragma unroll
    for (int j = 0; j < APT; ++j) {
      float lx = fmaxf(dv[j][0], t.x), ly = fmaxf(dv[j][1], t.y);
      float rx2 = fminf(dv[j][2], t.z), ry2 = fminf(dv[j][3], t.w);
      float iw = fmaxf(rx2 - lx, 0.0f), ih = fmaxf(ry2 - ly, 0.0f);
      float inter = iw * ih;
      float uni = areaA[j] + ab - inter;
      // inter/uni > bI/bU  <=>  inter*bU > bI*uni  (both unions > 0)
      if (inter * bU[j] > bI[j] * uni) { bI[j] = inter; bU[j] = uni; bM[j] = m; }
    }
  }

  // ---- finalize miou/midx, counts, hist ----
  float tv[APT];
  int   ti[APT];
  int cp = 0, cn = 0;
  #pragma unroll
  for (int j = 0; j < APT; ++j) {
    int n = n0 + j * 256;
    size_t idx = (size_t)b * NANCH + n;
    float q = bI[j] / fmaxf(bU[j], 1e-7f);   // IEEE, matches reference
    miou[idx] = q;
    midx[idx] = bM[j];
    tv[j] = q;
    ti[j] = n;
    bool p  = (q >= POS_THR);
    bool ng = (q < NEG_THR);
    cp += __popcll(__ballot(p));
    cn += __popcll(__ballot(ng));
    float sc = scores[idx];
    if (ng) {
      atomicAdd(&hist[(size_t)b * NBINS + score_bin(sc)], 1u);
    }
  }
  int lane = threadIdx.x & 63;
  if (lane == 0) {
    if (cp) atomicAdd(&pos_cnt[b], cp);
    if (cn) atomicAdd(&neg_cnt[b], cn);
  }

  // ---- barrier-free wave top-10 over the wave's 256 anchors ----
  int wid = threadIdx.x >> 6;
  size_t coff = ((size_t)(b * 64 + blk) * 4 + wid) * MIN_POS_TOPK;
  for (int it = 0; it < MIN_POS_TOPK; ++it) {
    float mv = tv[0]; int mi_ = ti[0];
    #pragma unroll
    for (int j = 1; j < APT; ++j) {
      if (tv[j] > mv || (tv[j] == mv && ti[j] < mi_)) { mv = tv[j]; mi_ = ti[j]; }
    }
    argmax64(mv, mi_);
    if (lane == 0) { cand_val[coff + it] = mv; cand_idx[coff + it] = mi_; }
    #pragma unroll
    for (int j = 0; j < APT; ++j) {
      if (ti[j] == mi_) tv[j] = -2.0f;
    }
  }
}

// ---------- K2 (fused): blocks 0..15 top-10 merge, blocks 16..31 bucket pick ----------
__global__ __launch_bounds__(256)
void k_mid(const float* __restrict__ cand_val, const int* __restrict__ cand_idx,
           const unsigned* __restrict__ hist,
           const int* __restrict__ pos_cnt, const int* __restrict__ neg_cnt,
           int* __restrict__ num_pos, int* __restrict__ use_fb,
           int* __restrict__ top10,
           int* __restrict__ subsample, int* __restrict__ bucket,
           int* __restrict__ below, int* __restrict__ total_samples) {
  if (blockIdx.x < NB) {
    // ---- top-10 merge over 2560 candidates ----
    int b = blockIdx.x;
    __shared__ float cv[NCAND];
    __shared__ int   ci[NCAND];
    __shared__ float swv[4];
    __shared__ int   swi[4];
    __shared__ int   sel[MIN_POS_TOPK];
    for (int j = threadIdx.x; j < NCAND; j += 256) {
      cv[j] = cand_val[(size_t)b * NCAND + j];
      ci[j] = cand_idx[(size_t)b * NCAND + j];
    }
    __syncthreads();
    int wid = threadIdx.x >> 6;
    for (int it = 0; it < MIN_POS_TOPK; ++it) {
      float v = -2.0f; int i = INT_MAX;
      for (int j = threadIdx.x; j < NCAND; j += 256) {
        if (cv[j] > v || (cv[j] == v && ci[j] < i)) { v = cv[j]; i = ci[j]; }
      }
      argmax64(v, i);
      if ((threadIdx.x & 63) == 0) { swv[wid] = v; swi[wid] = i; }
      __syncthreads();
      float bv = swv[0]; int bi = swi[0];
      #pragma unroll
      for (int w = 1; w < 4; ++w) {
        if (swv[w] > bv || (swv[w] == bv && swi[w] < bi)) { bv = swv[w]; bi = swi[w]; }
      }
      if (threadIdx.x == 0) sel[it] = bi;
      for (int j = threadIdx.x; j < NCAND; j += 256) {
        if (ci[j] == bi) cv[j] = -2.0f;
      }
      __syncthreads();
    }
    if (threadIdx.x < MIN_POS_TOPK) top10[b * MIN_POS_TOPK + threadIdx.x] = sel[threadIdx.x];
    if (threadIdx.x == 0) {
      int pc = pos_cnt[b];
      int fb = (pc < MIN_POS_TOPK) ? 1 : 0;
      use_fb[b] = fb;
      num_pos[b] = fb ? MIN_POS_TOPK : pc;
    }
  } else {
    // ---- bucket pick for negative subsampling ----
    int b = blockIdx.x - NB;
    int pc = pos_cnt[b];
    int np = (pc < MIN_POS_TOPK) ? MIN_POS_TOPK : pc;
    int nc = neg_cnt[b];
    int k = NEG_POS_RATIO * np;
    if (nc <= k) {
      if (threadIdx.x == 0) {
        subsample[b] = 0;
        bucket[b] = -1;
        below[b] = 0;
        total_samples[b] = np + nc;
      }
      return;
    }
    const unsigned* h = hist + (size_t)b * NBINS;
    __shared__ unsigned psum[256];
    unsigned s = 0;
    int seg0 = threadIdx.x * SEGSZ;
    for (int j = 0; j < SEGSZ; ++j) s += h[seg0 + j];
    psum[threadIdx.x] = s;
    __syncthreads();
    if (threadIdx.x == 0) {
      unsigned cum = 0;
      int seg = 255;
      for (int t = 0; t < 256; ++t) {
        if (cum + psum[t] >= (unsigned)k) { seg = t; break; }
        cum += psum[t];
      }
      unsigned c2 = cum;
      int bkt = seg * SEGSZ + SEGSZ - 1;
      for (int j = 0; j < SEGSZ; ++j) {
        unsigned hv = h[seg * SEGSZ + j];
        if (c2 + hv >= (unsigned)k) { bkt = seg * SEGSZ + j; break; }
        c2 += hv;
      }
      subsample[b] = 1;
      bucket[b] = bkt;
      below[b] = (int)c2;
      total_samples[b] = np + k;
    }
  }
}

// ---------- K3: gather boundary-bucket elements ----------
__global__ __launch_bounds__(256)
void k_gather(const float* __restrict__ miou, const float* __restrict__ scores,
              const int* __restrict__ subsample, const int* __restrict__ bucket,
              unsigned* __restrict__ eqb, int* __restrict__ eqi,
              int* __restrict__ eqcnt) {
  int b = blockIdx.x >> 8;
  if (!subsample[b]) return;
  int n = ((blockIdx.x & 255) << 8) | threadIdx.x;
  int bkt = bucket[b];
  size_t idx = (size_t)b * NANCH + n;
  if (miou[idx] < NEG_THR) {
    float sc = scores[idx];
    if ((int)score_bin(sc) == bkt) {
      int slot = atomicAdd(&eqcnt[b], 1);
      if (slot < EQCAP) {
        eqb[(size_t)b * EQCAP + slot] = __float_as_uint(sc);
        eqi[(size_t)b * EQCAP + slot] = n;
      }
    }
  }
}

// ---------- K4: rank within bucket -> exact cut (vbits, idx_cut) ----------
__global__ __launch_bounds__(256)
void k_rank(const unsigned* __restrict__ eqb, const int* __restrict__ eqi,
            const int* __restrict__ eqcnt, const int* __restrict__ subsample,
            const int* __restrict__ num_pos, const int* __restrict__ below,
            unsigned* __restrict__ vbits_out, int* __restrict__ idx_cut) {
  int b = blockIdx.x;
  if (!subsample[b]) {
    if (threadIdx.x == 0) { vbits_out[b] = 0u; idx_cut[b] = -1; }
    return;
  }
  int E = eqcnt[b]; if (E > EQCAP) E = EQCAP;
  int r = NEG_POS_RATIO * num_pos[b] - below[b];   // 1-based rank within bucket
  __shared__ unsigned sb_[EQCAP];
  __shared__ int      si_[EQCAP];
  for (int j = threadIdx.x; j < E; j += 256) {
    sb_[j] = eqb[(size_t)b * EQCAP + j];
    si_[j] = eqi[(size_t)b * EQCAP + j];
  }
  __syncthreads();
  for (int e = threadIdx.x; e < E; e += 256) {
    unsigned mb = sb_[e]; int mi = si_[e];
    int rank = 0;
    for (int j = 0; j < E; ++j) {
      unsigned ob = sb_[j]; int oi = si_[j];
      rank += (ob < mb || (ob == mb && oi < mi)) ? 1 : 0;
    }
    if (rank == r - 1) { vbits_out[b] = mb; idx_cut[b] = mi; }
  }
}

// ---------- K5: per-anchor loss accumulation ----------
__global__ __launch_bounds__(256)
void k_loss(const float* __restrict__ cls, const float* __restrict__ reg,
            const float* __restrict__ anchors, const float* __restrict__ tb,
            const int* __restrict__ tl, const float* __restrict__ scores,
            const float* __restrict__ miou, const int* __restrict__ midx,
            const int* __restrict__ use_fb, const int* __restrict__ top10,
            const int* __restrict__ subsample, const unsigned* __restrict__ vbits,
            const int* __restrict__ idx_cut,
            float* __restrict__ sums /* [NB][3] : pos, neg, reg */) {
  int b = blockIdx.x >> 8;
  int n = ((blockIdx.x & 255) << 8) | threadIdx.x;
  __shared__ int s_top10[MIN_POS_TOPK];
  __shared__ int s_usefb, s_sub, s_cut;
  __shared__ unsigned s_vb;
  __shared__ float accp, accn, accr;
  if (threadIdx.x < MIN_POS_TOPK) s_top10[threadIdx.x] = top10[b * MIN_POS_TOPK + threadIdx.x];
  if (threadIdx.x == 0) {
    s_usefb = use_fb[b]; s_sub = subsample[b]; s_cut = idx_cut[b]; s_vb = vbits[b];
    accp = 0.0f; accn = 0.0f; accr = 0.0f;
  }
  __syncthreads();

  size_t idx = (size_t)b * NANCH + n;
  float mi = miou[idx];

  bool pos;
  if (s_usefb) {
    pos = false;
    #pragma unroll
    for (int i = 0; i < MIN_POS_TOPK; ++i) pos |= (s_top10[i] == n);
  } else {
    pos = (mi >= POS_THR);
  }
  bool neg = (mi < NEG_THR);
  bool nsel = false;
  if (neg) {
    if (!s_sub) nsel = true;
    else {
      unsigned sb = __float_as_uint(scores[idx]);
      nsel = (sb < s_vb) || (sb == s_vb && n <= s_cut);
    }
  }

  float cp = 0.0f, cn = 0.0f, rg = 0.0f;
  if (pos || nsel) {
    int mx = 0, t = 0;
    if (pos) { mx = midx[idx]; t = tl[b * NM + mx]; }
    size_t cb = ((size_t)b * NC) * NANCH + n;
    float mxl = -3.0e38f, l0 = 0.0f, lt = 0.0f;
    for (int c = 0; c < NC; ++c) {
      float l = cls[cb + (size_t)c * NANCH];
      if (c == 0) l0 = l;
      if (c == t) lt = l;
      mxl = fmaxf(mxl, l);
    }
    float se = 0.0f;
    for (int c = 0; c < NC; ++c) {
      float l = cls[cb + (size_t)c * NANCH];
      se += expf(l - mxl);
    }
    float lse = mxl + logf(se);
    if (nsel) {
      float ce = lse - l0;
      float pt = expf(-ce);
      float om = 1.0f - pt;
      cn = F_ALPHA * om * om * ce;
    }
    if (pos) {
      float ce = lse - lt;
      float pt = expf(-ce);
      float om = 1.0f - pt;
      cp = F_ALPHA * om * om * ce;
      // decode + GIoU vs matched GT
      const float4 a4 = ((const float4*)anchors)[n];
      float aw = a4.z - a4.x, ah = a4.w - a4.y;
      float acx = a4.x + 0.5f * aw, acy = a4.y + 0.5f * ah;
      size_t rb = ((size_t)b * 4) * NANCH + n;
      float rx = reg[rb];
      float ry = reg[rb + (size_t)NANCH];
      float rw = reg[rb + 2 * (size_t)NANCH];
      float rh = reg[rb + 3 * (size_t)NANCH];
      float ccx = acx + rx * aw, ccy = acy + ry * ah;
      float w = aw * expf(rw), h = ah * expf(rh);
      float d0 = ccx - 0.5f * w, d1 = ccy - 0.5f * h;
      float d2 = ccx + 0.5f * w, d3 = ccy + 0.5f * h;
      const float* g = tb + ((size_t)b * NM + mx) * 4;
      float gx1 = g[0], gy1 = g[1], gx2 = g[2], gy2 = g[3];
      float area_a = (d2 - d0) * (d3 - d1);
      float area_b = (gx2 - gx1) * (gy2 - gy1);
      float lx = fmaxf(d0, gx1), ly = fmaxf(d1, gy1);
      float rx2 = fminf(d2, gx2), ry2 = fminf(d3, gy2);
      float iw = fmaxf(rx2 - lx, 0.0f), ih = fmaxf(ry2 - ly, 0.0f);
      float inter = iw * ih;
      float uni = area_a + area_b - inter;
      float iou = inter / fmaxf(uni, 1e-7f);
      float ex1 = fminf(d0, gx1), ey1 = fminf(d1, gy1);
      float ex2 = fmaxf(d2, gx2), ey2 = fmaxf(d3, gy2);
      float ew = fmaxf(ex2 - ex1, 0.0f), eh = fmaxf(ey2 - ey1, 0.0f);
      float enc = ew * eh;
      float giou = iou - (enc - uni) / fmaxf(enc, 1e-7f);
      rg = 1.0f - giou;
    }
  }

  if (cp != 0.0f) atomicAdd(&accp, cp);
  if (cn != 0.0f) atomicAdd(&accn, cn);
  if (rg != 0.0f) atomicAdd(&accr, rg);
  __syncthreads();
  if (threadIdx.x == 0) {
    if (accp != 0.0f) atomicAdd(&sums[b * 3 + 0], accp);
    if (accn != 0.0f) atomicAdd(&sums[b * 3 + 1], accn);
    if (accr != 0.0f) atomicAdd(&sums[b * 3 + 2], accr);
  }
}

// ---------- K6: finalize ----------
__global__ void k_final(const float* __restrict__ sums,
                        const int* __restrict__ total_samples,
                        const int* __restrict__ num_pos,
                        float* __restrict__ out) {
  if (threadIdx.x == 0 && blockIdx.x == 0) {
    float cm = 0.0f, rm = 0.0f;
    for (int b = 0; b < NB; ++b) {
      int ts = total_samples[b]; if (ts < 1) ts = 1;
      int np = num_pos[b]; if (np < 1) np = 1;
      cm += (sums[b * 3 + 0] + sums[b * 3 + 1]) / (float)ts;
      rm += sums[b * 3 + 2] / (float)np;
    }
    out[0] = cm / (float)NB + rm / (float)NB;
  }
}

extern "C" void kernel_launch(void* const* d_in, const int* in_sizes, int n_in,
                              void* d_out, int out_size, void* d_ws, size_t ws_size,
                              hipStream_t stream) {
  const float* cls     = (const float*)d_in[0];
  const float* reg     = (const float*)d_in[1];
  const float* anchors = (const float*)d_in[2];
  const float* tb      = (const float*)d_in[3];
  const int*   tl      = (const int*)d_in[4];
  const float* scores  = (const float*)d_in[5];
  float* out = (float*)d_out;

  char* ws = (char*)d_ws;
  size_t off = 0;
  float* miou = (float*)(ws + off);            off += (size_t)4 * NB * NANCH;
  int*   midx = (int*)(ws + off);              off += (size_t)4 * NB * NANCH;
  unsigned* hist = (unsigned*)(ws + off);      off += (size_t)4 * NB * NBINS;
  float* cand_val = (float*)(ws + off);        off += (size_t)4 * NB * NCAND;
  int*   cand_idx = (int*)(ws + off);          off += (size_t)4 * NB * NCAND;
  unsigned* eqb = (unsigned*)(ws + off);       off += (size_t)4 * NB * EQCAP;
  int*   eqi = (int*)(ws + off);               off += (size_t)4 * NB * EQCAP;
  int* scal = (int*)(ws + off);
  int* pos_cnt       = scal;
  int* neg_cnt       = scal + NB;
  int* num_pos       = scal + 2 * NB;
  int* use_fb        = scal + 3 * NB;
  int* subsample     = scal + 4 * NB;
  int* idx_cut       = scal + 5 * NB;
  unsigned* vbits    = (unsigned*)(scal + 6 * NB);
  int* total_samples = scal + 7 * NB;
  int* bucket        = scal + 8 * NB;
  int* below         = scal + 9 * NB;
  int* eqcnt         = scal + 10 * NB;
  int* top10         = scal + 11 * NB;                         // NB*10
  float* sums        = (float*)(scal + 11 * NB + MIN_POS_TOPK * NB); // NB*3

  k_init<<<256, 256, 0, stream>>>(hist, pos_cnt, neg_cnt, eqcnt, sums);
  k_iou<<<NB * 64, 256, 0, stream>>>(reg, anchors, tb, scores, miou, midx,
                                     pos_cnt, neg_cnt, hist, cand_val, cand_idx);
  k_mid<<<2 * NB, 256, 0, stream>>>(cand_val, cand_idx, hist, pos_cnt, neg_cnt,
                                    num_pos, use_fb, top10,
                                    subsample, bucket, below, total_samples);
  k_gather<<<NB * 256, 256, 0, stream>>>(miou, scores, subsample, bucket,
                                         eqb, eqi, eqcnt);
  k_rank<<<NB, 256, 0, stream>>>(eqb, eqi, eqcnt, subsample, num_pos, below,
                                 vbits, idx_cut);
  k_loss<<<NB * 256, 256, 0, stream>>>(cls, reg, anchors, tb, tl, scores,
                                       miou, midx, use_fb, top10, subsample,
                                       vbits, idx_cut, sums);
  k_final<<<1, 1, 0, stream>>>(sums, total_samples, num_pos, out);
}